// Round 9
// baseline (148.323 us; speedup 1.0000x reference)
//
#include <hip/hip_runtime.h>
#include <cstdint>

#define N_NODES 50000
#define N_EDGES 800000
#define F_IN    128
#define N_HEADS 4
#define HEAD_DIM 32
#define F_OUT   128

#define NBUCK   391                 // ceil(50000/128) coarse buckets (to>>7)
#define NPB     128                 // nodes per bucket
#define KA_GRID 512                 // binning blocks
#define EPB     1563                // ceil(800000/512) edges per binning block
#define EPB_PAD 1568                // blockarr stride (16-B aligned)
#define REC_CAP 2560                // rec_from region per bucket; mean 2048, ~11 sigma
#define STAGE_CAP REC_CAP
#define NSTRIP  (N_NODES / 16)      // 3125 (exact)
#define NGEMM   ((NSTRIP + 3) / 4)  // 782 gemm blocks (4 waves = 4 strips = 64 rows)
#define GB_GRID (NGEMM + NBUCK)     // 1173 blocks: b%3==0 build, else gemm

typedef unsigned int uint32;
typedef unsigned short ushort;
typedef __attribute__((ext_vector_type(8))) short short8v;   // 8 bf16 in 4 VGPRs
typedef __attribute__((ext_vector_type(4))) float float4v;

typedef __attribute__((address_space(1))) const ushort gushort;
typedef __attribute__((address_space(3))) ushort lushort;

__device__ __forceinline__ ushort f2bf(float f) {
    uint32 u = __float_as_uint(f);
    return (ushort)((u + 0x7FFFu + ((u >> 16) & 1u)) >> 16);   // RNE
}

// alpha slot permutation: head h -> slot {0->0, 1->2, 2->1, 3->3}
// so agg half-wave g reads (head g, head g+2) as one float2 at slot 2g.

// ---------------------------------------------------------------------------
// block-wide exclusive scan over 256 ints (4 waves)
// ---------------------------------------------------------------------------
__device__ __forceinline__ int block_scan_excl_256(int v, int* p_total)
{
    const int t = threadIdx.x, lane = t & 63, wv = t >> 6;
    int incl = v;
#pragma unroll
    for (int d = 1; d < 64; d <<= 1) {
        int u = __shfl_up(incl, d);
        if (lane >= d) incl += u;
    }
    __shared__ int wsum[4];
    if (lane == 63) wsum[wv] = incl;
    __syncthreads();
    int woff = 0;
#pragma unroll
    for (int j = 0; j < 4; ++j) {
        int s = wsum[j];
        if (j < wv) woff += s;
    }
    if (p_total) *p_total = wsum[0] + wsum[1] + wsum[2] + wsum[3];
    __syncthreads();
    return woff + incl - v;
}

// ---------------------------------------------------------------------------
// block-wide exclusive scan over 512 ints (8 waves) — bin path
// ---------------------------------------------------------------------------
__device__ __forceinline__ int block_scan_excl_512(int v)
{
    const int t = threadIdx.x, lane = t & 63, wv = t >> 6;
    int incl = v;
#pragma unroll
    for (int d = 1; d < 64; d <<= 1) {
        int u = __shfl_up(incl, d);
        if (lane >= d) incl += u;
    }
    __shared__ int wsum8[8];
    if (lane == 63) wsum8[wv] = incl;
    __syncthreads();
    int woff = 0;
#pragma unroll
    for (int j = 0; j < 8; ++j) {
        int s = wsum8[j];
        if (j < wv) woff += s;
    }
    __syncthreads();
    return woff + incl - v;
}

// ---------------------------------------------------------------------------
// k_bin_prep (R22 verbatim: one-pass ei — each thread's <=4 edges buffered
// in regs; both coalesced ei loads issue at entry so their latency hides
// under the LDS zero + scan; histogram and scatter run from registers).
// Blocks [0,KA_GRID): counting-sort 1563 edges in LDS, flush dense blockarr
// + b-major run directory. Blocks [KA_GRID, KA_GRID+4): W split into bf16
// hi/lo in MFMA B-fragment-sequential order: tile (nt,kt), lane l=(q,c15),
// elem j: W[kt*32+q*8+j][nt*16+c15]; WTF[tile*512 + l*8 + j] hi; +16384 lo.
// ---------------------------------------------------------------------------
__global__ __launch_bounds__(512) void k_bin_prep(
    const int* __restrict__ ei, const float* __restrict__ W,
    ushort* __restrict__ WTF,
    uint32* __restrict__ blockarr, int* __restrict__ cnts, int* __restrict__ offs)
{
    __shared__ int cur[512];                      // NBUCK padded
    __shared__ int off[512];
    __shared__ uint32 stg[EPB];

    if (blockIdx.x >= KA_GRID) {
        // ---------------- prep path ----------------
        const int id = (blockIdx.x - KA_GRID) * 512 + threadIdx.x;
        if (id >= 32 * 64) return;
        const int tile = id >> 6, l = id & 63;
        const int q = l >> 4, c15 = l & 15;
        const int nt = tile >> 2, kt = tile & 3;
        short8v hv, lv;
#pragma unroll
        for (int j = 0; j < 8; ++j) {
            const int k = kt * 32 + q * 8 + j;
            const float w = W[k * F_OUT + nt * 16 + c15];
            const ushort hi = f2bf(w);
            const float hif = __uint_as_float((uint32)hi << 16);
            hv[j] = (short)hi;
            lv[j] = (short)f2bf(w - hif);
        }
        *(short8v*)&WTF[tile * 512 + l * 8]         = hv;
        *(short8v*)&WTF[16384 + tile * 512 + l * 8] = lv;
        return;
    }

    // ---------------- bin path: one-pass local counting sort --------
    const int sb = blockIdx.x, t = threadIdx.x;
    const int e0 = sb * EPB;
    const int lim = min(EPB, N_EDGES - e0);

    int efrom[4], eto[4];                         // <=4 edges/thread in regs
#pragma unroll
    for (int j = 0; j < 4; ++j) {
        const int i = t + j * 512;
        if (i < lim) {
            efrom[j] = ei[e0 + i];                // coalesced, issued early
            eto[j]   = ei[N_EDGES + e0 + i];
        } else {
            efrom[j] = 0; eto[j] = -1;            // sentinel: skip
        }
    }

    cur[t] = 0;
    __syncthreads();

#pragma unroll
    for (int j = 0; j < 4; ++j)                   // histogram from regs
        if (eto[j] >= 0) atomicAdd(&cur[eto[j] >> 7], 1);
    __syncthreads();

    const int cv = cur[t];                        // one bucket per thread
    const int ex = block_scan_excl_512(cv);
    off[t] = ex;
    __syncthreads();

    if (t < NBUCK) {                              // run directory (b-major)
        cnts[(size_t)t * KA_GRID + sb] = cv;
        offs[(size_t)t * KA_GRID + sb] = ex;
    }
    __syncthreads();                              // directory read before cursor mutation

#pragma unroll
    for (int j = 0; j < 4; ++j) {                 // scatter from regs
        if (eto[j] >= 0) {
            const int pos = atomicAdd(&off[eto[j] >> 7], 1);
            stg[pos] = (uint32)efrom[j] | ((uint32)(eto[j] & 127) << 16);
        }
    }
    __syncthreads();

    uint32* dst = blockarr + (size_t)sb * EPB_PAD;
    for (int i = t; i < lim; i += 512)            // dense coalesced flush
        dst[i] = stg[i];
}

// ---------------------------------------------------------------------------
// k_gemm_build (R22 verbatim): 32 KB LDS = hi half of WTF; lo B-frags from
// global WTF (L2-hot); launch_bounds (256,4); x-loads hoisted before the
// global_load_lds staging so x's HBM latency drains pre-barrier.
// b%3==0 -> build for bucket b/3; else -> gemm strip group.
// ---------------------------------------------------------------------------
__global__ __launch_bounds__(256, 4) void k_gemm_build(
    const float* __restrict__ x, const ushort* __restrict__ WTF,
    const float* __restrict__ attl, const float* __restrict__ attr,
    const uint32* __restrict__ blockarr,
    const int* __restrict__ cnts, const int* __restrict__ offs,
    uint32* __restrict__ hbq, float* __restrict__ aLp, float* __restrict__ aRp,
    int* __restrict__ count, int* __restrict__ offsets, int* __restrict__ rec_from)
{
    __shared__ __attribute__((aligned(16))) char lds_buf[32768];

    if (blockIdx.x % 3 == 0) {
        // ---------------- build path ----------------
        uint32* stage = (uint32*)lds_buf;                 // [STAGE_CAP] 10 KB
        int*    hist  = (int*)(lds_buf + STAGE_CAP * 4);  // [NPB]
        int*    curn  = hist + NPB;                       // [NPB]
        const int b = blockIdx.x / 3, t = threadIdx.x;

        int c[2], o[2];
#pragma unroll
        for (int j = 0; j < 2; ++j) {             // coalesced directory row
            c[j] = cnts[(size_t)b * KA_GRID + 2 * t + j];
            o[j] = offs[(size_t)b * KA_GRID + 2 * t + j];
        }
        int total;
        int ex = block_scan_excl_256(c[0] + c[1], &total);
        if (t < NPB) hist[t] = 0;
        __syncthreads();

#pragma unroll
        for (int j = 0; j < 2; ++j) {             // gather dense runs
            const int sb = 2 * t + j;
            const uint32* src = blockarr + (size_t)sb * EPB_PAD + o[j];
            for (int i = 0; i < c[j]; ++i) {
                const int p = ex + i;
                if (p < STAGE_CAP) stage[p] = src[i];
            }
            ex += c[j];
        }
        __syncthreads();

        const int S = min(total, STAGE_CAP);
        for (int i = t; i < S; i += 256) atomicAdd(&hist[stage[i] >> 16], 1);
        __syncthreads();

        const int hv = (t < NPB) ? hist[t] : 0;
        int tot2;
        const int lo = block_scan_excl_256(hv, &tot2);
        const int rbase = b * REC_CAP;
        const int n = b * NPB + t;
        if (t < NPB && n < N_NODES) {
            count[n]   = hv;
            offsets[n] = rbase + lo;
        }
        if (t < NPB) curn[t] = lo;
        __syncthreads();

        for (int i = t; i < S; i += 256) {
            const uint32 e = stage[i];
            const int pos = atomicAdd(&curn[e >> 16], 1);
            rec_from[rbase + pos] = (int)(e & 0xFFFFu);
        }
        return;
    }

    // ---------------- gemm path ----------------
    const int bid   = blockIdx.x - blockIdx.x / 3 - 1;   // 0..781
    const int lane  = threadIdx.x & 63;
    const int wv    = threadIdx.x >> 6;
    const int q     = lane >> 4;
    const int c15   = lane & 15;

    const int strip = bid * 4 + wv;
    const int row0  = strip * 16;

    // x loads first: latency drains under the WTF staging + barrier.
    float4 xf[8];
    if (strip < NSTRIP) {
        const float* xrow = x + (size_t)(row0 + c15) * F_IN + q * 8;
#pragma unroll
        for (int kt = 0; kt < 4; ++kt) {
            xf[kt * 2]     = *(const float4*)(xrow + kt * 32);
            xf[kt * 2 + 1] = *(const float4*)(xrow + kt * 32 + 4);
        }
    }

    ushort* wt = (ushort*)lds_buf;                // hi half only (32 KB)
#pragma unroll
    for (int i = 0; i < 8; ++i) {
        const int chunk = wv * 8 + i;
        __builtin_amdgcn_global_load_lds(
            (gushort*)(WTF + chunk * 512 + lane * 8),
            (lushort*)(wt + chunk * 512), 16, 0, 0);
    }
    __syncthreads();

    if (strip >= NSTRIP) return;                  // wave-uniform exit

    short8v ahi[4], alo[4];
#pragma unroll
    for (int kt = 0; kt < 4; ++kt) {
        const float4 f0 = xf[kt * 2];
        const float4 f1 = xf[kt * 2 + 1];
        const float fs[8] = {f0.x, f0.y, f0.z, f0.w, f1.x, f1.y, f1.z, f1.w};
#pragma unroll
        for (int j = 0; j < 8; ++j) {
            const ushort hi = f2bf(fs[j]);
            const float hif = __uint_as_float((uint32)hi << 16);
            ahi[kt][j] = (short)hi;
            alo[kt][j] = (short)f2bf(fs[j] - hif);
        }
    }

    const ushort* wlo = WTF + 16384;              // lo half: global, L2-hot
    float4v acc[8];
#pragma unroll
    for (int nt = 0; nt < 8; ++nt) {
        float4v a = {0.f, 0.f, 0.f, 0.f};
#pragma unroll
        for (int kt = 0; kt < 4; ++kt) {
            const short8v bh = *(const short8v*)(wt + (nt * 4 + kt) * 512 + lane * 8);
            const short8v bl = *(const short8v*)(wlo + (nt * 4 + kt) * 512 + lane * 8);
            a = __builtin_amdgcn_mfma_f32_16x16x32_bf16(ahi[kt], bh, a, 0, 0, 0);
            a = __builtin_amdgcn_mfma_f32_16x16x32_bf16(alo[kt], bh, a, 0, 0, 0);
            a = __builtin_amdgcn_mfma_f32_16x16x32_bf16(ahi[kt], bl, a, 0, 0, 0);
        }
        acc[nt] = a;
    }

#pragma unroll
    for (int nt = 0; nt < 4; ++nt) {
#pragma unroll
        for (int r = 0; r < 4; ++r) {
            const uint32 d = (uint32)f2bf(acc[nt][r]) | ((uint32)f2bf(acc[nt + 4][r]) << 16);
            hbq[(size_t)(row0 + q * 4 + r) * 64 + nt * 16 + c15] = d;
        }
    }

    float aLacc[4][4] = {{0.f}}, aRacc[4][4] = {{0.f}};
#pragma unroll
    for (int nt = 0; nt < 8; ++nt) {
        const float alv = attl[nt * 16 + c15];
        const float arv = attr[nt * 16 + c15];
        const int hh = nt >> 1;
#pragma unroll
        for (int r = 0; r < 4; ++r) {
            aLacc[r][hh] = fmaf(acc[nt][r], alv, aLacc[r][hh]);
            aRacc[r][hh] = fmaf(acc[nt][r], arv, aRacc[r][hh]);
        }
    }
#pragma unroll
    for (int r = 0; r < 4; ++r) {
#pragma unroll
        for (int hh = 0; hh < 4; ++hh) {
            float vl = aLacc[r][hh], vr = aRacc[r][hh];
#pragma unroll
            for (int d = 1; d < 16; d <<= 1) {
                vl += __shfl_xor(vl, d);
                vr += __shfl_xor(vr, d);
            }
            if (c15 == hh) {
                const int row = row0 + q * 4 + r;
                const int pos = (hh & 1) * 2 + (hh >> 1);   // permuted slot
                aLp[row * N_HEADS + pos] = vl;
                aRp[row * N_HEADS + pos] = vr;
            }
        }
    }
}

// ---------------------------------------------------------------------------
// k_agg (R23: + isolated 16-deep gather tier — the R19 variable without the
// KA_GRID confound). Wave per node; lane l owns dims (l, l+64) via hbq word
// l — heads = permuted alpha slots (hsel, hsel+1). Half-wave exp dedup via
// shfl. 16-tier: issue all 16 f-shuffles then 16 hbq loads (4 KB/wave in
// flight, 2x the 8-tier); e-shuffles deferred into the consume loop so live
// state is f[16]+h[16] (~+32 VGPR). Deg mean 16 -> most nodes issue their
// whole edge list in one batch. Accumulation order identical to two
// 8-batches -> bit-identical numerics.
// ---------------------------------------------------------------------------
__global__ __launch_bounds__(256) void k_agg(const int* __restrict__ rec_from,
    const int* __restrict__ count, const int* __restrict__ offsets,
    const float* __restrict__ aLp, const float* __restrict__ aRp,
    const uint32* __restrict__ hbq,
    const float* __restrict__ bias, float* __restrict__ out)
{
    const int lane = threadIdx.x & 63;
    const int n = blockIdx.x * 4 + (threadIdx.x >> 6);
    if (n >= N_NODES) return;
    const int cnt  = count[n];
    const int off  = offsets[n];
    const int hsel = (lane >> 5) * 2;   // permuted slot pair for this half-wave
    const int l31  = lane & 31;
    const int gsel = lane & 32;
    const float2 arv = *(const float2*)&aRp[n * N_HEADS + hsel];
    float ax = 0.f, ay = 0.f, ds0 = 0.f, ds1 = 0.f;

    for (int base = 0; base < cnt; base += 32) {
        const int m = min(32, cnt - base);
        int vf = 0;
        float e0p = 0.f, e1p = 0.f;
        if (l31 < m) {
            vf = rec_from[off + base + l31];                  // coalesced
            const float2 af = *(const float2*)&aLp[vf * N_HEADS + hsel];
            float t0 = af.x + arv.x; t0 = (t0 > 0.f) ? t0 : 0.2f * t0;
            float t1 = af.y + arv.y; t1 = (t1 > 0.f) ? t1 : 0.2f * t1;
            e0p = __expf(t0);
            e1p = __expf(t1);
        }
        int i = 0;
        for (; i + 16 <= m; i += 16) {
            int f[16]; uint32 h[16];
#pragma unroll
            for (int j = 0; j < 16; ++j) f[j] = __shfl(vf, gsel | (i + j));
#pragma unroll
            for (int j = 0; j < 16; ++j) h[j] = hbq[(size_t)f[j] * 64 + lane];
#pragma unroll
            for (int j = 0; j < 16; ++j) {
                const int s = gsel | (i + j);
                const float e0 = __shfl(e0p, s);
                const float e1 = __shfl(e1p, s);
                ax = fmaf(e0, __uint_as_float(h[j] << 16), ax);
                ay = fmaf(e1, __uint_as_float(h[j] & 0xFFFF0000u), ay);
                ds0 += e0; ds1 += e1;
            }
        }
        for (; i + 8 <= m; i += 8) {
            int f[8]; uint32 h[8]; float e0[8], e1[8];
#pragma unroll
            for (int j = 0; j < 8; ++j) {
                const int s = gsel | (i + j);
                f[j]  = __shfl(vf, s);
                e0[j] = __shfl(e0p, s);
                e1[j] = __shfl(e1p, s);
            }
#pragma unroll
            for (int j = 0; j < 8; ++j) h[j] = hbq[(size_t)f[j] * 64 + lane];
#pragma unroll
            for (int j = 0; j < 8; ++j) {
                ax = fmaf(e0[j], __uint_as_float(h[j] << 16), ax);
                ay = fmaf(e1[j], __uint_as_float(h[j] & 0xFFFF0000u), ay);
                ds0 += e0[j]; ds1 += e1[j];
            }
        }
        for (; i + 4 <= m; i += 4) {
            int f[4]; uint32 h[4]; float e0[4], e1[4];
#pragma unroll
            for (int j = 0; j < 4; ++j) {
                const int s = gsel | (i + j);
                f[j]  = __shfl(vf, s);
                e0[j] = __shfl(e0p, s);
                e1[j] = __shfl(e1p, s);
            }
#pragma unroll
            for (int j = 0; j < 4; ++j) h[j] = hbq[(size_t)f[j] * 64 + lane];
#pragma unroll
            for (int j = 0; j < 4; ++j) {
                ax = fmaf(e0[j], __uint_as_float(h[j] << 16), ax);
                ay = fmaf(e1[j], __uint_as_float(h[j] & 0xFFFF0000u), ay);
                ds0 += e0[j]; ds1 += e1[j];
            }
        }
        for (; i < m; ++i) {
            const int s = gsel | i;
            const int f = __shfl(vf, s);
            const uint32 hv = hbq[(size_t)f * 64 + lane];
            const float e0 = __shfl(e0p, s), e1 = __shfl(e1p, s);
            ax = fmaf(e0, __uint_as_float(hv << 16), ax);
            ay = fmaf(e1, __uint_as_float(hv & 0xFFFF0000u), ay);
            ds0 += e0; ds1 += e1;
        }
    }
    const float inv0 = 1.0f / (ds0 + 1e-9f);
    const float inv1 = 1.0f / (ds1 + 1e-9f);
    out[n * F_OUT + lane]      = ax * inv0 + bias[lane];
    out[n * F_OUT + 64 + lane] = ay * inv1 + bias[64 + lane];
}

// ---------------------------------------------------------------------------
extern "C" void kernel_launch(void* const* d_in, const int* in_sizes, int n_in,
                              void* d_out, int out_size, void* d_ws, size_t ws_size,
                              hipStream_t stream)
{
    const float* x    = (const float*)d_in[0];
    const int*   ei   = (const int*)d_in[1];
    const float* W    = (const float*)d_in[2];
    const float* attl = (const float*)d_in[3];
    const float* attr = (const float*)d_in[4];
    const float* bias = (const float*)d_in[5];
    float* out = (float*)d_out;

    char* p = (char*)d_ws;
    auto carve = [&](size_t bytes) -> char* {
        char* q = p;
        p += (bytes + 255) & ~size_t(255);
        return q;
    };
    // total ~23.7 MB
    uint32* hbq      = (uint32*)carve((size_t)N_NODES * 64 * 4);           // 12.8 MB
    uint32* blockarr = (uint32*)carve((size_t)KA_GRID * EPB_PAD * 4);      // 3.2 MB
    int*    rec_from = (int*)carve((size_t)NBUCK * REC_CAP * 4);           // 4.0 MB
    ushort* WTF      = (ushort*)carve(32768 * 2);                          // 64 KB
    float*  aLp      = (float*)carve((size_t)N_NODES * N_HEADS * 4);
    float*  aRp      = (float*)carve((size_t)N_NODES * N_HEADS * 4);
    int*    cnts     = (int*)carve((size_t)NBUCK * KA_GRID * 4);           // 0.8 MB
    int*    offs     = (int*)carve((size_t)NBUCK * KA_GRID * 4);           // 0.8 MB
    int*    count    = (int*)carve((size_t)N_NODES * 4);
    int*    offsets  = (int*)carve((size_t)N_NODES * 4);

    k_bin_prep<<<KA_GRID + 4, 512, 0, stream>>>(ei, W, WTF, blockarr, cnts, offs);
    k_gemm_build<<<GB_GRID, 256, 0, stream>>>(x, WTF, attl, attr,
                                              blockarr, cnts, offs,
                                              hbq, aLp, aRp,
                                              count, offsets, rec_from);
    k_agg<<<(N_NODES + 3) / 4, 256, 0, stream>>>(rec_from, count, offsets,
                                                 aLp, aRp, hbq, bias, out);
}

// Round 11
// 144.772 us; speedup vs baseline: 1.0245x; 1.0245x over previous
//
#include <hip/hip_runtime.h>
#include <cstdint>

#define N_NODES 50000
#define N_EDGES 800000
#define F_IN    128
#define N_HEADS 4
#define HEAD_DIM 32
#define F_OUT   128

#define NBUCK   391                 // ceil(50000/128) coarse buckets (to>>7)
#define NPB     128                 // nodes per bucket
#define KA_GRID 512                 // binning blocks
#define EPB     1563                // ceil(800000/512) edges per binning block
#define EPB_PAD 1568                // blockarr stride (16-B aligned)
#define REC_CAP 2560                // rec_from region per bucket; mean 2048, ~11 sigma
#define STAGE_CAP REC_CAP
#define NSTRIP  (N_NODES / 16)      // 3125 (exact)
#define NGEMM   ((NSTRIP + 3) / 4)  // 782 gemm blocks (4 waves = 4 strips = 64 rows)
#define GB_GRID (NGEMM + NBUCK)     // 1173 blocks: b%3==0 build, else gemm

typedef unsigned int uint32;
typedef unsigned short ushort;
typedef __attribute__((ext_vector_type(8))) short short8v;   // 8 bf16 in 4 VGPRs
typedef __attribute__((ext_vector_type(4))) float float4v;

typedef __attribute__((address_space(1))) const ushort gushort;
typedef __attribute__((address_space(3))) ushort lushort;

__device__ __forceinline__ ushort f2bf(float f) {
    uint32 u = __float_as_uint(f);
    return (ushort)((u + 0x7FFFu + ((u >> 16) & 1u)) >> 16);   // RNE
}

// alpha slot permutation: head h -> slot {0->0, 1->2, 2->1, 3->3}
// so agg half-wave g reads (head g, head g+2) as one float2 at slot 2g.

// ---------------------------------------------------------------------------
// block-wide exclusive scan over 256 ints (4 waves)
// ---------------------------------------------------------------------------
__device__ __forceinline__ int block_scan_excl_256(int v, int* p_total)
{
    const int t = threadIdx.x, lane = t & 63, wv = t >> 6;
    int incl = v;
#pragma unroll
    for (int d = 1; d < 64; d <<= 1) {
        int u = __shfl_up(incl, d);
        if (lane >= d) incl += u;
    }
    __shared__ int wsum[4];
    if (lane == 63) wsum[wv] = incl;
    __syncthreads();
    int woff = 0;
#pragma unroll
    for (int j = 0; j < 4; ++j) {
        int s = wsum[j];
        if (j < wv) woff += s;
    }
    if (p_total) *p_total = wsum[0] + wsum[1] + wsum[2] + wsum[3];
    __syncthreads();
    return woff + incl - v;
}

// ---------------------------------------------------------------------------
// block-wide exclusive scan over 512 ints (8 waves) — bin path
// ---------------------------------------------------------------------------
__device__ __forceinline__ int block_scan_excl_512(int v)
{
    const int t = threadIdx.x, lane = t & 63, wv = t >> 6;
    int incl = v;
#pragma unroll
    for (int d = 1; d < 64; d <<= 1) {
        int u = __shfl_up(incl, d);
        if (lane >= d) incl += u;
    }
    __shared__ int wsum8[8];
    if (lane == 63) wsum8[wv] = incl;
    __syncthreads();
    int woff = 0;
#pragma unroll
    for (int j = 0; j < 8; ++j) {
        int s = wsum8[j];
        if (j < wv) woff += s;
    }
    __syncthreads();
    return woff + incl - v;
}

// ---------------------------------------------------------------------------
// k_bin_prep (one-pass ei — each thread's <=4 edges buffered in regs;
// both coalesced ei loads issue at entry so their latency hides under the
// LDS zero + scan; histogram and scatter run from registers, no re-read).
// Blocks [0,KA_GRID): counting-sort 1563 edges in LDS, flush dense blockarr
// + b-major run directory. Blocks [KA_GRID, KA_GRID+4): W split into bf16
// hi/lo in MFMA B-fragment-sequential order: tile (nt,kt), lane l=(q,c15),
// elem j: W[kt*32+q*8+j][nt*16+c15]; WTF[tile*512 + l*8 + j] hi; +16384 lo.
// ---------------------------------------------------------------------------
__global__ __launch_bounds__(512) void k_bin_prep(
    const int* __restrict__ ei, const float* __restrict__ W,
    ushort* __restrict__ WTF,
    uint32* __restrict__ blockarr, int* __restrict__ cnts, int* __restrict__ offs)
{
    __shared__ int cur[512];                      // NBUCK padded
    __shared__ int off[512];
    __shared__ uint32 stg[EPB];

    if (blockIdx.x >= KA_GRID) {
        // ---------------- prep path ----------------
        const int id = (blockIdx.x - KA_GRID) * 512 + threadIdx.x;
        if (id >= 32 * 64) return;
        const int tile = id >> 6, l = id & 63;
        const int q = l >> 4, c15 = l & 15;
        const int nt = tile >> 2, kt = tile & 3;
        short8v hv, lv;
#pragma unroll
        for (int j = 0; j < 8; ++j) {
            const int k = kt * 32 + q * 8 + j;
            const float w = W[k * F_OUT + nt * 16 + c15];
            const ushort hi = f2bf(w);
            const float hif = __uint_as_float((uint32)hi << 16);
            hv[j] = (short)hi;
            lv[j] = (short)f2bf(w - hif);
        }
        *(short8v*)&WTF[tile * 512 + l * 8]         = hv;
        *(short8v*)&WTF[16384 + tile * 512 + l * 8] = lv;
        return;
    }

    // ---------------- bin path: one-pass local counting sort --------
    const int sb = blockIdx.x, t = threadIdx.x;
    const int e0 = sb * EPB;
    const int lim = min(EPB, N_EDGES - e0);

    int efrom[4], eto[4];                         // <=4 edges/thread in regs
#pragma unroll
    for (int j = 0; j < 4; ++j) {
        const int i = t + j * 512;
        if (i < lim) {
            efrom[j] = ei[e0 + i];                // coalesced, issued early
            eto[j]   = ei[N_EDGES + e0 + i];
        } else {
            efrom[j] = 0; eto[j] = -1;            // sentinel: skip
        }
    }

    cur[t] = 0;
    __syncthreads();

#pragma unroll
    for (int j = 0; j < 4; ++j)                   // histogram from regs
        if (eto[j] >= 0) atomicAdd(&cur[eto[j] >> 7], 1);
    __syncthreads();

    const int cv = cur[t];                        // one bucket per thread
    const int ex = block_scan_excl_512(cv);
    off[t] = ex;
    __syncthreads();

    if (t < NBUCK) {                              // run directory (b-major)
        cnts[(size_t)t * KA_GRID + sb] = cv;
        offs[(size_t)t * KA_GRID + sb] = ex;
    }
    __syncthreads();                              // directory read before cursor mutation

#pragma unroll
    for (int j = 0; j < 4; ++j) {                 // scatter from regs
        if (eto[j] >= 0) {
            const int pos = atomicAdd(&off[eto[j] >> 7], 1);
            stg[pos] = (uint32)efrom[j] | ((uint32)(eto[j] & 127) << 16);
        }
    }
    __syncthreads();

    uint32* dst = blockarr + (size_t)sb * EPB_PAD;
    for (int i = t; i < lim; i += 512)            // dense coalesced flush
        dst[i] = stg[i];
}

// ---------------------------------------------------------------------------
// k_gemm_build: 32 KB LDS = hi half of WTF; lo B-frags from global WTF
// (L2-hot); launch_bounds (256,4); x-loads hoisted before the
// global_load_lds staging so x's HBM latency drains pre-barrier.
// b%3==0 -> build for bucket b/3; else -> gemm strip group.
// ---------------------------------------------------------------------------
__global__ __launch_bounds__(256, 4) void k_gemm_build(
    const float* __restrict__ x, const ushort* __restrict__ WTF,
    const float* __restrict__ attl, const float* __restrict__ attr,
    const uint32* __restrict__ blockarr,
    const int* __restrict__ cnts, const int* __restrict__ offs,
    uint32* __restrict__ hbq, float* __restrict__ aLp, float* __restrict__ aRp,
    int* __restrict__ count, int* __restrict__ offsets, int* __restrict__ rec_from)
{
    __shared__ __attribute__((aligned(16))) char lds_buf[32768];

    if (blockIdx.x % 3 == 0) {
        // ---------------- build path ----------------
        uint32* stage = (uint32*)lds_buf;                 // [STAGE_CAP] 10 KB
        int*    hist  = (int*)(lds_buf + STAGE_CAP * 4);  // [NPB]
        int*    curn  = hist + NPB;                       // [NPB]
        const int b = blockIdx.x / 3, t = threadIdx.x;

        int c[2], o[2];
#pragma unroll
        for (int j = 0; j < 2; ++j) {             // coalesced directory row
            c[j] = cnts[(size_t)b * KA_GRID + 2 * t + j];
            o[j] = offs[(size_t)b * KA_GRID + 2 * t + j];
        }
        int total;
        int ex = block_scan_excl_256(c[0] + c[1], &total);
        if (t < NPB) hist[t] = 0;
        __syncthreads();

#pragma unroll
        for (int j = 0; j < 2; ++j) {             // gather dense runs
            const int sb = 2 * t + j;
            const uint32* src = blockarr + (size_t)sb * EPB_PAD + o[j];
            for (int i = 0; i < c[j]; ++i) {
                const int p = ex + i;
                if (p < STAGE_CAP) stage[p] = src[i];
            }
            ex += c[j];
        }
        __syncthreads();

        const int S = min(total, STAGE_CAP);
        for (int i = t; i < S; i += 256) atomicAdd(&hist[stage[i] >> 16], 1);
        __syncthreads();

        const int hv = (t < NPB) ? hist[t] : 0;
        int tot2;
        const int lo = block_scan_excl_256(hv, &tot2);
        const int rbase = b * REC_CAP;
        const int n = b * NPB + t;
        if (t < NPB && n < N_NODES) {
            count[n]   = hv;
            offsets[n] = rbase + lo;
        }
        if (t < NPB) curn[t] = lo;
        __syncthreads();

        for (int i = t; i < S; i += 256) {
            const uint32 e = stage[i];
            const int pos = atomicAdd(&curn[e >> 16], 1);
            rec_from[rbase + pos] = (int)(e & 0xFFFFu);
        }
        return;
    }

    // ---------------- gemm path ----------------
    const int bid   = blockIdx.x - blockIdx.x / 3 - 1;   // 0..781
    const int lane  = threadIdx.x & 63;
    const int wv    = threadIdx.x >> 6;
    const int q     = lane >> 4;
    const int c15   = lane & 15;

    const int strip = bid * 4 + wv;
    const int row0  = strip * 16;

    // x loads first: latency drains under the WTF staging + barrier.
    float4 xf[8];
    if (strip < NSTRIP) {
        const float* xrow = x + (size_t)(row0 + c15) * F_IN + q * 8;
#pragma unroll
        for (int kt = 0; kt < 4; ++kt) {
            xf[kt * 2]     = *(const float4*)(xrow + kt * 32);
            xf[kt * 2 + 1] = *(const float4*)(xrow + kt * 32 + 4);
        }
    }

    ushort* wt = (ushort*)lds_buf;                // hi half only (32 KB)
#pragma unroll
    for (int i = 0; i < 8; ++i) {
        const int chunk = wv * 8 + i;
        __builtin_amdgcn_global_load_lds(
            (gushort*)(WTF + chunk * 512 + lane * 8),
            (lushort*)(wt + chunk * 512), 16, 0, 0);
    }
    __syncthreads();

    if (strip >= NSTRIP) return;                  // wave-uniform exit

    short8v ahi[4], alo[4];
#pragma unroll
    for (int kt = 0; kt < 4; ++kt) {
        const float4 f0 = xf[kt * 2];
        const float4 f1 = xf[kt * 2 + 1];
        const float fs[8] = {f0.x, f0.y, f0.z, f0.w, f1.x, f1.y, f1.z, f1.w};
#pragma unroll
        for (int j = 0; j < 8; ++j) {
            const ushort hi = f2bf(fs[j]);
            const float hif = __uint_as_float((uint32)hi << 16);
            ahi[kt][j] = (short)hi;
            alo[kt][j] = (short)f2bf(fs[j] - hif);
        }
    }

    const ushort* wlo = WTF + 16384;              // lo half: global, L2-hot
    float4v acc[8];
#pragma unroll
    for (int nt = 0; nt < 8; ++nt) {
        float4v a = {0.f, 0.f, 0.f, 0.f};
#pragma unroll
        for (int kt = 0; kt < 4; ++kt) {
            const short8v bh = *(const short8v*)(wt + (nt * 4 + kt) * 512 + lane * 8);
            const short8v bl = *(const short8v*)(wlo + (nt * 4 + kt) * 512 + lane * 8);
            a = __builtin_amdgcn_mfma_f32_16x16x32_bf16(ahi[kt], bh, a, 0, 0, 0);
            a = __builtin_amdgcn_mfma_f32_16x16x32_bf16(alo[kt], bh, a, 0, 0, 0);
            a = __builtin_amdgcn_mfma_f32_16x16x32_bf16(ahi[kt], bl, a, 0, 0, 0);
        }
        acc[nt] = a;
    }

#pragma unroll
    for (int nt = 0; nt < 4; ++nt) {
#pragma unroll
        for (int r = 0; r < 4; ++r) {
            const uint32 d = (uint32)f2bf(acc[nt][r]) | ((uint32)f2bf(acc[nt + 4][r]) << 16);
            hbq[(size_t)(row0 + q * 4 + r) * 64 + nt * 16 + c15] = d;
        }
    }

    float aLacc[4][4] = {{0.f}}, aRacc[4][4] = {{0.f}};
#pragma unroll
    for (int nt = 0; nt < 8; ++nt) {
        const float alv = attl[nt * 16 + c15];
        const float arv = attr[nt * 16 + c15];
        const int hh = nt >> 1;
#pragma unroll
        for (int r = 0; r < 4; ++r) {
            aLacc[r][hh] = fmaf(acc[nt][r], alv, aLacc[r][hh]);
            aRacc[r][hh] = fmaf(acc[nt][r], arv, aRacc[r][hh]);
        }
    }
#pragma unroll
    for (int r = 0; r < 4; ++r) {
#pragma unroll
        for (int hh = 0; hh < 4; ++hh) {
            float vl = aLacc[r][hh], vr = aRacc[r][hh];
#pragma unroll
            for (int d = 1; d < 16; d <<= 1) {
                vl += __shfl_xor(vl, d);
                vr += __shfl_xor(vr, d);
            }
            if (c15 == hh) {
                const int row = row0 + q * 4 + r;
                const int pos = (hh & 1) * 2 + (hh >> 1);   // permuted slot
                aLp[row * N_HEADS + pos] = vl;
                aRp[row * N_HEADS + pos] = vr;
            }
        }
    }
}

// ---------------------------------------------------------------------------
// k_agg (8-deep MLP — measured floor; R23's 16-deep tier regressed).
// Wave per node; lane l owns dims (l, l+64) via hbq word l — heads =
// permuted alpha slots (hsel, hsel+1). Half-wave exp dedup via shfl.
// Softmax max-shift cancels in ex/sum(ex); att <= ~10 so no fp32 overflow.
// ---------------------------------------------------------------------------
__global__ __launch_bounds__(256) void k_agg(const int* __restrict__ rec_from,
    const int* __restrict__ count, const int* __restrict__ offsets,
    const float* __restrict__ aLp, const float* __restrict__ aRp,
    const uint32* __restrict__ hbq,
    const float* __restrict__ bias, float* __restrict__ out)
{
    const int lane = threadIdx.x & 63;
    const int n = blockIdx.x * 4 + (threadIdx.x >> 6);
    if (n >= N_NODES) return;
    const int cnt  = count[n];
    const int off  = offsets[n];
    const int hsel = (lane >> 5) * 2;   // permuted slot pair for this half-wave
    const int l31  = lane & 31;
    const int gsel = lane & 32;
    const float2 arv = *(const float2*)&aRp[n * N_HEADS + hsel];
    float ax = 0.f, ay = 0.f, ds0 = 0.f, ds1 = 0.f;

    for (int base = 0; base < cnt; base += 32) {
        const int m = min(32, cnt - base);
        int vf = 0;
        float e0p = 0.f, e1p = 0.f;
        if (l31 < m) {
            vf = rec_from[off + base + l31];                  // coalesced
            const float2 af = *(const float2*)&aLp[vf * N_HEADS + hsel];
            float t0 = af.x + arv.x; t0 = (t0 > 0.f) ? t0 : 0.2f * t0;
            float t1 = af.y + arv.y; t1 = (t1 > 0.f) ? t1 : 0.2f * t1;
            e0p = __expf(t0);
            e1p = __expf(t1);
        }
        int i = 0;
        for (; i + 8 <= m; i += 8) {
            int f[8]; uint32 h[8]; float e0[8], e1[8];
#pragma unroll
            for (int j = 0; j < 8; ++j) {
                const int s = gsel | (i + j);
                f[j]  = __shfl(vf, s);
                e0[j] = __shfl(e0p, s);
                e1[j] = __shfl(e1p, s);
            }
#pragma unroll
            for (int j = 0; j < 8; ++j) h[j] = hbq[(size_t)f[j] * 64 + lane];
#pragma unroll
            for (int j = 0; j < 8; ++j) {
                ax = fmaf(e0[j], __uint_as_float(h[j] << 16), ax);
                ay = fmaf(e1[j], __uint_as_float(h[j] & 0xFFFF0000u), ay);
                ds0 += e0[j]; ds1 += e1[j];
            }
        }
        for (; i + 4 <= m; i += 4) {
            int f[4]; uint32 h[4]; float e0[4], e1[4];
#pragma unroll
            for (int j = 0; j < 4; ++j) {
                const int s = gsel | (i + j);
                f[j]  = __shfl(vf, s);
                e0[j] = __shfl(e0p, s);
                e1[j] = __shfl(e1p, s);
            }
#pragma unroll
            for (int j = 0; j < 4; ++j) h[j] = hbq[(size_t)f[j] * 64 + lane];
#pragma unroll
            for (int j = 0; j < 4; ++j) {
                ax = fmaf(e0[j], __uint_as_float(h[j] << 16), ax);
                ay = fmaf(e1[j], __uint_as_float(h[j] & 0xFFFF0000u), ay);
                ds0 += e0[j]; ds1 += e1[j];
            }
        }
        for (; i < m; ++i) {
            const int s = gsel | i;
            const int f = __shfl(vf, s);
            const uint32 hv = hbq[(size_t)f * 64 + lane];
            const float e0 = __shfl(e0p, s), e1 = __shfl(e1p, s);
            ax = fmaf(e0, __uint_as_float(hv << 16), ax);
            ay = fmaf(e1, __uint_as_float(hv & 0xFFFF0000u), ay);
            ds0 += e0; ds1 += e1;
        }
    }
    const float inv0 = 1.0f / (ds0 + 1e-9f);
    const float inv1 = 1.0f / (ds1 + 1e-9f);
    out[n * F_OUT + lane]      = ax * inv0 + bias[lane];
    out[n * F_OUT + 64 + lane] = ay * inv1 + bias[64 + lane];
}

// ---------------------------------------------------------------------------
extern "C" void kernel_launch(void* const* d_in, const int* in_sizes, int n_in,
                              void* d_out, int out_size, void* d_ws, size_t ws_size,
                              hipStream_t stream)
{
    const float* x    = (const float*)d_in[0];
    const int*   ei   = (const int*)d_in[1];
    const float* W    = (const float*)d_in[2];
    const float* attl = (const float*)d_in[3];
    const float* attr = (const float*)d_in[4];
    const float* bias = (const float*)d_in[5];
    float* out = (float*)d_out;

    char* p = (char*)d_ws;
    auto carve = [&](size_t bytes) -> char* {
        char* q = p;
        p += (bytes + 255) & ~size_t(255);
        return q;
    };
    // total ~23.7 MB
    uint32* hbq      = (uint32*)carve((size_t)N_NODES * 64 * 4);           // 12.8 MB
    uint32* blockarr = (uint32*)carve((size_t)KA_GRID * EPB_PAD * 4);      // 3.2 MB
    int*    rec_from = (int*)carve((size_t)NBUCK * REC_CAP * 4);           // 4.0 MB
    ushort* WTF      = (ushort*)carve(32768 * 2);                          // 64 KB
    float*  aLp      = (float*)carve((size_t)N_NODES * N_HEADS * 4);
    float*  aRp      = (float*)carve((size_t)N_NODES * N_HEADS * 4);
    int*    cnts     = (int*)carve((size_t)NBUCK * KA_GRID * 4);           // 0.8 MB
    int*    offs     = (int*)carve((size_t)NBUCK * KA_GRID * 4);           // 0.8 MB
    int*    count    = (int*)carve((size_t)N_NODES * 4);
    int*    offsets  = (int*)carve((size_t)N_NODES * 4);

    k_bin_prep<<<KA_GRID + 4, 512, 0, stream>>>(ei, W, WTF, blockarr, cnts, offs);
    k_gemm_build<<<GB_GRID, 256, 0, stream>>>(x, WTF, attl, attr,
                                              blockarr, cnts, offs,
                                              hbq, aLp, aRp,
                                              count, offsets, rec_from);
    k_agg<<<(N_NODES + 3) / 4, 256, 0, stream>>>(rec_from, count, offsets,
                                                 aLp, aRp, hbq, bias, out);
}